// Round 1
// baseline (2133.002 us; speedup 1.0000x reference)
//
#include <hip/hip_runtime.h>
#include <math.h>

#define B 2048
#define H 1024
#define NC 4

// ---------------------------------------------------------------------------
// fp32 tiled GEMM: C[m, z*1024 + n] = sum_k A[m,k] * W[z][k,n]
// A: (2048 x 1024) row-major. W: (nz x 1024 x 1024). C row stride = ldc.
// Tile 128x128, BK=16, 256 threads, 8x8 per thread.
// ---------------------------------------------------------------------------
__global__ __launch_bounds__(256, 2) void gemm_kernel(
    const float* __restrict__ A, const float* __restrict__ W,
    float* __restrict__ C, int ldc)
{
    const int K = 1024, N = 1024;
    const int bz = blockIdx.z;
    const float* Wb = W + (size_t)bz * K * N;
    const int m0 = blockIdx.y * 128;
    const int n0 = blockIdx.x * 128;

    __shared__ __align__(16) float As[16][128];  // As[kk][mm] (A transposed)
    __shared__ __align__(16) float Bs[16][128];  // Bs[kk][nn]

    const int tid = threadIdx.x;
    const int tm = (tid / 16) * 8;
    const int tn = (tid % 16) * 8;

    float acc[8][8];
#pragma unroll
    for (int i = 0; i < 8; i++)
#pragma unroll
        for (int j = 0; j < 8; j++) acc[i][j] = 0.f;

    for (int k0 = 0; k0 < K; k0 += 16) {
        // Stage A tile: 128 rows x 16 cols = 512 float4, 2 per thread
#pragma unroll
        for (int l = 0; l < 2; l++) {
            int f = tid * 2 + l;          // 0..511
            int row = f >> 2;             // 0..127
            int c4 = f & 3;               // 0..3
            float4 v = *(const float4*)(A + (size_t)(m0 + row) * K + k0 + c4 * 4);
            As[c4 * 4 + 0][row] = v.x;
            As[c4 * 4 + 1][row] = v.y;
            As[c4 * 4 + 2][row] = v.z;
            As[c4 * 4 + 3][row] = v.w;
        }
        // Stage B tile: 16 rows x 128 cols = 512 float4, 2 per thread
#pragma unroll
        for (int l = 0; l < 2; l++) {
            int f = tid * 2 + l;
            int row = f >> 5;             // 0..15
            int c4 = f & 31;              // 0..31
            *(float4*)(&Bs[row][c4 * 4]) =
                *(const float4*)(Wb + (size_t)(k0 + row) * N + n0 + c4 * 4);
        }
        __syncthreads();
#pragma unroll
        for (int kk = 0; kk < 16; kk++) {
            float a[8], bv[8];
            *(float4*)(a)      = *(const float4*)(&As[kk][tm]);
            *(float4*)(a + 4)  = *(const float4*)(&As[kk][tm + 4]);
            *(float4*)(bv)     = *(const float4*)(&Bs[kk][tn]);
            *(float4*)(bv + 4) = *(const float4*)(&Bs[kk][tn + 4]);
#pragma unroll
            for (int i = 0; i < 8; i++)
#pragma unroll
                for (int j = 0; j < 8; j++)
                    acc[i][j] = fmaf(a[i], bv[j], acc[i][j]);
        }
        __syncthreads();
    }

#pragma unroll
    for (int i = 0; i < 8; i++) {
        float* Cp = C + (size_t)(m0 + tm + i) * ldc + (size_t)bz * 1024 + n0 + tn;
        float4 o0 = make_float4(acc[i][0], acc[i][1], acc[i][2], acc[i][3]);
        float4 o1 = make_float4(acc[i][4], acc[i][5], acc[i][6], acc[i][7]);
        *(float4*)(Cp)     = o0;
        *(float4*)(Cp + 4) = o1;
    }
}

// ---------------------------------------------------------------------------
// E0: z1 = sigmoid(xsL[:,0,:] + hsR[:,0,:] + b[0]); r = sigmoid(xsL[:,1,:] + hsR[:,1,:] + b[1])
// ---------------------------------------------------------------------------
__global__ __launch_bounds__(256) void e0_kernel(
    const float* __restrict__ xsL, const float* __restrict__ hsR,
    const float* __restrict__ bias,
    float* __restrict__ z1, float* __restrict__ r)
{
    size_t idx = (size_t)blockIdx.x * 256 + threadIdx.x;  // over B*H
    int b = (int)(idx >> 10);
    int h = (int)(idx & 1023);
    float a0 = xsL[(size_t)b * 4096 + h];
    float a1 = xsL[(size_t)b * 4096 + 1024 + h];
    float c0 = hsR[(size_t)b * 2048 + h];
    float c1 = hsR[(size_t)b * 2048 + 1024 + h];
    float b0 = bias[h];
    float b1 = bias[1024 + h];
    z1[idx] = 1.f / (1.f + expf(-(a0 + c0 + b0)));
    r[idx]  = 1.f / (1.f + expf(-(a1 + c1 + b1)));
}

__global__ __launch_bounds__(256) void zero_g_kernel(float* __restrict__ G)
{
    int idx = blockIdx.x * 256 + threadIdx.x;
    if (idx < B * 9) G[idx] = 0.f;
}

__device__ __forceinline__ float wave_red(float v)
{
#pragma unroll
    for (int o = 32; o; o >>= 1) v += __shfl_down(v, o, 64);
    return v;
}

// ---------------------------------------------------------------------------
// E1: three mixes sharing inputs:
//   rh  = mix(hsL * rR  + b)  -> G[:,3]
//   omz = mix(1 - (z1R + b))  -> G[:,5]
//   z2h = mix(hsL * z1R + b)  -> G[:,7]
// one block per batch row; 256 threads, 4 h per thread.
// ---------------------------------------------------------------------------
__global__ __launch_bounds__(256) void mix3_kernel(
    const float* __restrict__ hsL, const float* __restrict__ rR,
    const float* __restrict__ z1R, const float* __restrict__ bias,
    const float* __restrict__ w,
    float* __restrict__ rh, float* __restrict__ omz, float* __restrict__ z2h,
    float* __restrict__ G)
{
    const int b = blockIdx.x, tid = threadIdx.x;
    const size_t base = (size_t)b * 4096;
    float v[3][4][4];
    float sc[3][4];
#pragma unroll
    for (int m = 0; m < 3; m++)
#pragma unroll
        for (int k = 0; k < 4; k++) sc[m][k] = 0.f;

#pragma unroll
    for (int k = 0; k < 4; k++) {
#pragma unroll
        for (int i = 0; i < 4; i++) {
            int h = tid + i * 256;
            float hl = hsL[base + k * 1024 + h];
            float rr = rR [base + k * 1024 + h];
            float zr = z1R[base + k * 1024 + h];
            float bk = bias[k * 1024 + h];
            float wv = w[h];
            float a = fmaf(hl, rr, bk);
            float c = 1.0f - (zr + bk);
            float d = fmaf(hl, zr, bk);
            v[0][k][i] = a; v[1][k][i] = c; v[2][k][i] = d;
            sc[0][k] = fmaf(a, wv, sc[0][k]);
            sc[1][k] = fmaf(c, wv, sc[1][k]);
            sc[2][k] = fmaf(d, wv, sc[2][k]);
        }
    }
    __shared__ float red[12][4];
    const int wid = tid >> 6, lane = tid & 63;
#pragma unroll
    for (int m = 0; m < 3; m++)
#pragma unroll
        for (int k = 0; k < 4; k++) {
            float s = wave_red(sc[m][k]);
            if (lane == 0) red[m * 4 + k][wid] = s;
        }
    __syncthreads();
    __shared__ float probs[3][4];
    if (tid < 3) {
        int m = tid;
        float s[4];
#pragma unroll
        for (int k = 0; k < 4; k++)
            s[k] = red[m * 4 + k][0] + red[m * 4 + k][1] + red[m * 4 + k][2] + red[m * 4 + k][3];
        int am = 0; float mx = s[0];
#pragma unroll
        for (int k = 1; k < 4; k++) if (s[k] > mx) { mx = s[k]; am = k; }
        float e[4], tot = 0.f;
#pragma unroll
        for (int k = 0; k < 4; k++) { e[k] = expf(s[k] - mx); tot += e[k]; }
#pragma unroll
        for (int k = 0; k < 4; k++) probs[m][k] = e[k] / tot;
        int gcol = (m == 0) ? 3 : (m == 1) ? 5 : 7;
        G[(size_t)b * 9 + gcol] = (float)am;
    }
    __syncthreads();
    float p[3][4];
#pragma unroll
    for (int m = 0; m < 3; m++)
#pragma unroll
        for (int k = 0; k < 4; k++) p[m][k] = probs[m][k];
#pragma unroll
    for (int i = 0; i < 4; i++) {
        int h = tid + i * 256;
        float o0 = 0, o1 = 0, o2 = 0;
#pragma unroll
        for (int k = 0; k < 4; k++) {
            o0 = fmaf(p[0][k], v[0][k][i], o0);
            o1 = fmaf(p[1][k], v[1][k][i], o1);
            o2 = fmaf(p[2][k], v[2][k][i], o2);
        }
        rh [(size_t)b * 1024 + h] = o0;
        omz[(size_t)b * 1024 + h] = o1;
        z2h[(size_t)b * 1024 + h] = o2;
    }
}

// ---------------------------------------------------------------------------
// Generic mix: OP=0: p*q+b ; OP=1: tanh(p+q+b) ; OP=2: p+q+b
// ---------------------------------------------------------------------------
template <int OP>
__global__ __launch_bounds__(256) void mix_kernel(
    const float* __restrict__ P, const float* __restrict__ Q,
    const float* __restrict__ bias, const float* __restrict__ w,
    float* __restrict__ out, float* __restrict__ G, int gcol)
{
    const int b = blockIdx.x, tid = threadIdx.x;
    const size_t base = (size_t)b * 4096;
    float v[4][4];
    float sc[4] = {0.f, 0.f, 0.f, 0.f};
#pragma unroll
    for (int k = 0; k < 4; k++) {
#pragma unroll
        for (int i = 0; i < 4; i++) {
            int h = tid + i * 256;
            float pp = P[base + k * 1024 + h];
            float qq = Q[base + k * 1024 + h];
            float bk = bias[k * 1024 + h];
            float wv = w[h];
            float val;
            if (OP == 0)      val = fmaf(pp, qq, bk);
            else if (OP == 1) val = tanhf(pp + qq + bk);
            else              val = pp + qq + bk;
            v[k][i] = val;
            sc[k] = fmaf(val, wv, sc[k]);
        }
    }
    __shared__ float red[4][4];
    const int wid = tid >> 6, lane = tid & 63;
#pragma unroll
    for (int k = 0; k < 4; k++) {
        float s = wave_red(sc[k]);
        if (lane == 0) red[k][wid] = s;
    }
    __syncthreads();
    __shared__ float probs[4];
    if (tid == 0) {
        float s[4];
#pragma unroll
        for (int k = 0; k < 4; k++)
            s[k] = red[k][0] + red[k][1] + red[k][2] + red[k][3];
        int am = 0; float mx = s[0];
#pragma unroll
        for (int k = 1; k < 4; k++) if (s[k] > mx) { mx = s[k]; am = k; }
        float e[4], tot = 0.f;
#pragma unroll
        for (int k = 0; k < 4; k++) { e[k] = expf(s[k] - mx); tot += e[k]; }
#pragma unroll
        for (int k = 0; k < 4; k++) probs[k] = e[k] / tot;
        G[(size_t)b * 9 + gcol] = (float)am;
    }
    __syncthreads();
    float p0 = probs[0], p1 = probs[1], p2 = probs[2], p3 = probs[3];
#pragma unroll
    for (int i = 0; i < 4; i++) {
        int h = tid + i * 256;
        float o = p0 * v[0][i];
        o = fmaf(p1, v[1][i], o);
        o = fmaf(p2, v[2][i], o);
        o = fmaf(p3, v[3][i], o);
        out[(size_t)b * 1024 + h] = o;
    }
}

// ---------------------------------------------------------------------------
extern "C" void kernel_launch(void* const* d_in, const int* in_sizes, int n_in,
                              void* d_out, int out_size, void* d_ws, size_t ws_size,
                              hipStream_t stream)
{
    const float* xs   = (const float*)d_in[0];  // (B,1,H) == (B,H)
    const float* hs   = (const float*)d_in[1];
    const float* L    = (const float*)d_in[2];  // (4,H,H)
    const float* R    = (const float*)d_in[3];
    const float* bias = (const float*)d_in[4];  // (4,H) -- zeros, kept for exactness
    const float* w    = (const float*)d_in[5];  // (H,)

    float* out = (float*)d_out;                 // h_next: B*H floats
    float* G   = out + (size_t)B * H;           // G: B*9 "floats" (int values)

    float* ws = (float*)d_ws;
    const size_t S4 = (size_t)B * 4 * H;  // 8 M floats = 32 MB
    const size_t S1 = (size_t)B * H;      // 2 M floats = 8 MB
    // buffer reuse schedule (see journal): peak = 4*S4 + 5*S1 = 168 MB
    float* bufA = ws;            // xsL                       (alive S0..E2)
    float* bufB = ws + S4;       // hsL -> rhR -> htL
    float* bufC = ws + 2 * S4;   // rR  -> omzR -> zhL
    float* bufD = ws + 3 * S4;   // hsR2 -> z1R -> z2hR
    float* s1 = ws + 4 * S4;     // z1 -> h_tilde
    float* s2 = s1 + S1;         // r  -> zh_tilde
    float* s3 = s2 + S1;         // rh
    float* s4 = s3 + S1;         // one_minus_z1
    float* s5 = s4 + S1;         // z2h

    dim3 g4(8, 16, 4), g2(8, 16, 2);
    dim3 blk(256);

    zero_g_kernel<<<(B * 9 + 255) / 256, blk, 0, stream>>>(G);

    // S0
    gemm_kernel<<<g4, blk, 0, stream>>>(xs, L, bufA, 4096);  // xsL
    gemm_kernel<<<g2, blk, 0, stream>>>(hs, R, bufD, 2048);  // hsR (k=0,1)
    gemm_kernel<<<g4, blk, 0, stream>>>(hs, L, bufB, 4096);  // hsL
    // E0
    e0_kernel<<<(B * H) / 256, blk, 0, stream>>>(bufA, bufD, bias, s1, s2);
    // S1
    gemm_kernel<<<g4, blk, 0, stream>>>(s1, R, bufD, 4096);  // z1R (= z2R)
    gemm_kernel<<<g4, blk, 0, stream>>>(s2, R, bufC, 4096);  // rR
    // E1: rh (G3), one_minus_z1 (G5), z2h (G7)
    mix3_kernel<<<B, blk, 0, stream>>>(bufB, bufC, bufD, bias, w, s3, s4, s5, G);
    // S2
    gemm_kernel<<<g4, blk, 0, stream>>>(s3, R, bufB, 4096);  // rhR
    gemm_kernel<<<g4, blk, 0, stream>>>(s4, R, bufC, 4096);  // omzR
    // E2: h_tilde = mix(tanh(xsL + rhR + b)) (G4)
    mix_kernel<1><<<B, blk, 0, stream>>>(bufA, bufB, bias, w, s1, G, 4);
    // S3
    gemm_kernel<<<g4, blk, 0, stream>>>(s1, L, bufB, 4096);  // htL
    gemm_kernel<<<g4, blk, 0, stream>>>(s5, R, bufD, 4096);  // z2hR
    // E3: zh_tilde = mix(htL * omzR + b) (G6)
    mix_kernel<0><<<B, blk, 0, stream>>>(bufB, bufC, bias, w, s2, G, 6);
    // S4
    gemm_kernel<<<g4, blk, 0, stream>>>(s2, L, bufC, 4096);  // zhL
    // E4: h_next = mix(zhL + z2hR + b) (G8) -> d_out
    mix_kernel<2><<<B, blk, 0, stream>>>(bufC, bufD, bias, w, out, G, 8);
}

// Round 2
// 685.575 us; speedup vs baseline: 3.1113x; 3.1113x over previous
//
#include <hip/hip_runtime.h>
#include <math.h>

#define B 2048
#define H 1024

typedef __attribute__((ext_vector_type(8))) short bf16x8;
typedef __attribute__((ext_vector_type(4))) float floatx4;

// ---------------- bf16 split helpers (RNE) ----------------
__device__ __forceinline__ short bf16_rne(float x) {
    unsigned int b = __float_as_uint(x);
    unsigned int r = (b + 0x7fffu + ((b >> 16) & 1u)) >> 16;
    return (short)r;
}
__device__ __forceinline__ float bf16_f(short h) {
    return __uint_as_float(((unsigned int)(unsigned short)h) << 16);
}
__device__ __forceinline__ void split2(float x, short& h, short& l) {
    h = bf16_rne(x);
    l = bf16_rne(x - bf16_f(h));
}

// async global->LDS, 16B per lane; LDS dest = wave-uniform base + lane*16
__device__ __forceinline__ void gl16(const void* g, void* l) {
    __builtin_amdgcn_global_load_lds(
        (const __attribute__((address_space(1))) void*)g,
        (__attribute__((address_space(3))) void*)l, 16, 0, 0);
}

// ---------------------------------------------------------------------------
// Split-bf16 GEMM: C[m, z*1024+n] = sum_k A[m,k]*W[z][k,n], A=Ah+Al, W=Bh+Bl.
// A: [2048][1024] bf16 hi/lo row-major. B*: Wt[z][n][k] bf16 (pre-transposed).
// 128x128 tile, BK=32, 256 thr (2x2 waves, each 4x4 of 16x16x32 MFMA).
// 4-term product => fp32-class accuracy. LDS chunk-XOR swizzle: position
// cpos holds global k-chunk (cpos ^ ((row>>1)&3)) -> frag reads 2-way only.
// ---------------------------------------------------------------------------
__global__ __launch_bounds__(256, 2) void gemm_kernel(
    const short* __restrict__ Ah, const short* __restrict__ Al,
    const short* __restrict__ Bh, const short* __restrict__ Bl,
    float* __restrict__ C, int ldc)
{
    __shared__ short lds[4][4096];  // Ah,Al,Bh,Bl tiles: [128 rows][32 k] 8KB each
    const int tid = threadIdx.x;
    const int w = tid >> 6, lane = tid & 63;
    const int wm = w >> 1, wn = w & 1;
    const int m0 = blockIdx.y * 128, n0 = blockIdx.x * 128;
    const int z = blockIdx.z;

    // staging: chunk id cid = j*256+tid; row=cid>>2, cpos=cid&3,
    // source k-chunk = cpos ^ ((row>>1)&3) = (cid&3)^((cid>>3)&3)
    const int cid0 = tid, cid1 = 256 + tid;
    const int r0 = cid0 >> 2, g0 = (((cid0 & 3) ^ ((cid0 >> 3) & 3)) << 3);
    const int r1 = cid1 >> 2, g1 = (((cid1 & 3) ^ ((cid1 >> 3) & 3)) << 3);

    const short* pah0 = Ah + (size_t)(m0 + r0) * H + g0;
    const short* pah1 = Ah + (size_t)(m0 + r1) * H + g1;
    const short* pal0 = Al + (size_t)(m0 + r0) * H + g0;
    const short* pal1 = Al + (size_t)(m0 + r1) * H + g1;
    const size_t wb = (size_t)z * H * H;
    const short* pbh0 = Bh + wb + (size_t)(n0 + r0) * H + g0;
    const short* pbh1 = Bh + wb + (size_t)(n0 + r1) * H + g1;
    const short* pbl0 = Bl + wb + (size_t)(n0 + r0) * H + g0;
    const short* pbl1 = Bl + wb + (size_t)(n0 + r1) * H + g1;

    short* sA0 = &lds[0][w * 512];        short* sA1 = &lds[0][2048 + w * 512];
    short* sa0 = &lds[1][w * 512];        short* sa1 = &lds[1][2048 + w * 512];
    short* sB0 = &lds[2][w * 512];        short* sB1 = &lds[2][2048 + w * 512];
    short* sb0 = &lds[3][w * 512];        short* sb1 = &lds[3][2048 + w * 512];

    // fragment LDS offsets (shorts), constant across k-steps
    const int fr = lane & 15, kc = lane >> 4;
    int aoff[4], boff[4];
#pragma unroll
    for (int t = 0; t < 4; t++) {
        int ar = wm * 64 + t * 16 + fr;
        aoff[t] = ar * 32 + ((kc ^ ((ar >> 1) & 3)) << 3);
        int br = wn * 64 + t * 16 + fr;
        boff[t] = br * 32 + ((kc ^ ((br >> 1) & 3)) << 3);
    }

    floatx4 acc[4][4];
#pragma unroll
    for (int i = 0; i < 4; i++)
#pragma unroll
        for (int j = 0; j < 4; j++) acc[i][j] = (floatx4)0.f;

    for (int ks = 0; ks < 32; ks++) {
        __syncthreads();  // previous iteration's LDS reads done
        gl16(pah0, sA0); gl16(pah1, sA1);
        gl16(pal0, sa0); gl16(pal1, sa1);
        gl16(pbh0, sB0); gl16(pbh1, sB1);
        gl16(pbl0, sb0); gl16(pbl1, sb1);
        pah0 += 32; pah1 += 32; pal0 += 32; pal1 += 32;
        pbh0 += 32; pbh1 += 32; pbl0 += 32; pbl1 += 32;
        __syncthreads();  // vmcnt(0) drain + barrier

        bf16x8 fah[4], fal[4], fbh[4], fbl[4];
#pragma unroll
        for (int t = 0; t < 4; t++) {
            fah[t] = *(const bf16x8*)&lds[0][aoff[t]];
            fal[t] = *(const bf16x8*)&lds[1][aoff[t]];
            fbh[t] = *(const bf16x8*)&lds[2][boff[t]];
            fbl[t] = *(const bf16x8*)&lds[3][boff[t]];
        }
#pragma unroll
        for (int mt = 0; mt < 4; mt++)
#pragma unroll
            for (int nt = 0; nt < 4; nt++) {
                acc[mt][nt] = __builtin_amdgcn_mfma_f32_16x16x32_bf16(fah[mt], fbh[nt], acc[mt][nt], 0, 0, 0);
                acc[mt][nt] = __builtin_amdgcn_mfma_f32_16x16x32_bf16(fah[mt], fbl[nt], acc[mt][nt], 0, 0, 0);
                acc[mt][nt] = __builtin_amdgcn_mfma_f32_16x16x32_bf16(fal[mt], fbh[nt], acc[mt][nt], 0, 0, 0);
                acc[mt][nt] = __builtin_amdgcn_mfma_f32_16x16x32_bf16(fal[mt], fbl[nt], acc[mt][nt], 0, 0, 0);
            }
    }

    // C/D layout (m89/m91): col = lane&15, row = (lane>>4)*4 + reg
    const int cr = (lane >> 4) * 4, cc = lane & 15;
#pragma unroll
    for (int mt = 0; mt < 4; mt++)
#pragma unroll
        for (int nt = 0; nt < 4; nt++) {
            float* Cp = C + (size_t)(m0 + wm * 64 + mt * 16 + cr) * ldc
                          + (size_t)z * 1024 + n0 + wn * 64 + nt * 16 + cc;
#pragma unroll
            for (int i = 0; i < 4; i++) Cp[(size_t)i * ldc] = acc[mt][nt][i];
        }
}

// ---------------------------------------------------------------------------
// weights: W[z][k][n] fp32 -> Wt_hi/lo[z][n][k] bf16 (transpose + split)
// ---------------------------------------------------------------------------
__global__ __launch_bounds__(256) void wsplit_kernel(
    const float* __restrict__ L, const float* __restrict__ R,
    short* __restrict__ Lth, short* __restrict__ Ltl,
    short* __restrict__ Rth, short* __restrict__ Rtl)
{
    const int zz = blockIdx.z;  // 0-3: L, 4-7: R
    const float* W = (zz < 4) ? L : R;
    short* Oh = (zz < 4) ? Lth : Rth;
    short* Ol = (zz < 4) ? Ltl : Rtl;
    const int z = zz & 3;
    const int k0 = blockIdx.y * 32, n0 = blockIdx.x * 32;
    __shared__ float t[32][33];
    const int tx = threadIdx.x & 31, ty = threadIdx.x >> 5;  // ty 0..7
    const float* src = W + (size_t)z * 1048576;
#pragma unroll
    for (int j = 0; j < 4; j++) {
        int r = ty + j * 8;
        t[r][tx] = src[(size_t)(k0 + r) * 1024 + n0 + tx];
    }
    __syncthreads();
    short* oh = Oh + (size_t)z * 1048576;
    short* ol = Ol + (size_t)z * 1048576;
#pragma unroll
    for (int j = 0; j < 4; j++) {
        int n = ty + j * 8;
        float v = t[tx][n];
        short hh, ll; split2(v, hh, ll);
        oh[(size_t)(n0 + n) * 1024 + k0 + tx] = hh;
        ol[(size_t)(n0 + n) * 1024 + k0 + tx] = ll;
    }
}

// inputs xs, hs -> bf16 hi/lo
__global__ __launch_bounds__(256) void conv_kernel(
    const float* __restrict__ xs, const float* __restrict__ hs,
    short* __restrict__ xh, short* __restrict__ xl,
    short* __restrict__ hh, short* __restrict__ hl)
{
    size_t i = (size_t)blockIdx.x * 256 + threadIdx.x;
    short a, b2; split2(xs[i], a, b2); xh[i] = a; xl[i] = b2;
    split2(hs[i], a, b2); hh[i] = a; hl[i] = b2;
}

__global__ __launch_bounds__(256) void zero_g_kernel(float* __restrict__ G)
{
    int idx = blockIdx.x * 256 + threadIdx.x;
    if (idx < B * 9) G[idx] = 0.f;  // G written as float bits; harness reads fp32 (R1 passed)
}

// z1 = sigmoid(xsL0+hsR0+b0), r = sigmoid(xsL1+hsR1+b1) -> bf16 hi/lo
__global__ __launch_bounds__(256) void e0_kernel(
    const float* __restrict__ xsL, const float* __restrict__ hsR,
    const float* __restrict__ bias,
    short* __restrict__ z1h, short* __restrict__ z1l,
    short* __restrict__ rh_, short* __restrict__ rl_)
{
    size_t idx = (size_t)blockIdx.x * 256 + threadIdx.x;
    int b = (int)(idx >> 10), h = (int)(idx & 1023);
    float z1 = 1.f / (1.f + expf(-(xsL[(size_t)b * 4096 + h] + hsR[(size_t)b * 2048 + h] + bias[h])));
    float r  = 1.f / (1.f + expf(-(xsL[(size_t)b * 4096 + 1024 + h] + hsR[(size_t)b * 2048 + 1024 + h] + bias[1024 + h])));
    short hh, ll;
    split2(z1, hh, ll); z1h[idx] = hh; z1l[idx] = ll;
    split2(r, hh, ll);  rh_[idx] = hh; rl_[idx] = ll;
}

__device__ __forceinline__ float wave_red(float v)
{
#pragma unroll
    for (int o = 32; o; o >>= 1) v += __shfl_down(v, o, 64);
    return v;
}

// ---------------------------------------------------------------------------
// mix2: omz = mix(1-(z1R+b)) -> G5 ; z2h = mix(hsL*z1R+b) -> G7. bf16 hi/lo out.
// ---------------------------------------------------------------------------
__global__ __launch_bounds__(256) void mix2_kernel(
    const float* __restrict__ hsL, const float* __restrict__ z1R,
    const float* __restrict__ bias, const float* __restrict__ wsc,
    short* __restrict__ omzh, short* __restrict__ omzl,
    short* __restrict__ z2hh, short* __restrict__ z2hl,
    float* __restrict__ G)
{
    const int b = blockIdx.x, tid = threadIdx.x;
    const size_t base = (size_t)b * 4096;
    float v[2][4][4], sc[2][4];
#pragma unroll
    for (int m = 0; m < 2; m++)
#pragma unroll
        for (int k = 0; k < 4; k++) sc[m][k] = 0.f;
#pragma unroll
    for (int k = 0; k < 4; k++)
#pragma unroll
        for (int i = 0; i < 4; i++) {
            int h = tid + i * 256;
            float hl = hsL[base + k * 1024 + h];
            float zr = z1R[base + k * 1024 + h];
            float bk = bias[k * 1024 + h];
            float wv = wsc[h];
            float c = 1.0f - (zr + bk);
            float d = fmaf(hl, zr, bk);
            v[0][k][i] = c; v[1][k][i] = d;
            sc[0][k] = fmaf(c, wv, sc[0][k]);
            sc[1][k] = fmaf(d, wv, sc[1][k]);
        }
    __shared__ float red[8][4];
    const int wid = tid >> 6, lane = tid & 63;
#pragma unroll
    for (int m = 0; m < 2; m++)
#pragma unroll
        for (int k = 0; k < 4; k++) {
            float s = wave_red(sc[m][k]);
            if (lane == 0) red[m * 4 + k][wid] = s;
        }
    __syncthreads();
    __shared__ float probs[2][4];
    if (tid < 2) {
        int m = tid;
        float s[4];
#pragma unroll
        for (int k = 0; k < 4; k++)
            s[k] = red[m * 4 + k][0] + red[m * 4 + k][1] + red[m * 4 + k][2] + red[m * 4 + k][3];
        int am = 0; float mx = s[0];
#pragma unroll
        for (int k = 1; k < 4; k++) if (s[k] > mx) { mx = s[k]; am = k; }
        float e[4], tot = 0.f;
#pragma unroll
        for (int k = 0; k < 4; k++) { e[k] = expf(s[k] - mx); tot += e[k]; }
#pragma unroll
        for (int k = 0; k < 4; k++) probs[m][k] = e[k] / tot;
        G[(size_t)b * 9 + (m == 0 ? 5 : 7)] = (float)am;
    }
    __syncthreads();
    float p0[4], p1[4];
#pragma unroll
    for (int k = 0; k < 4; k++) { p0[k] = probs[0][k]; p1[k] = probs[1][k]; }
#pragma unroll
    for (int i = 0; i < 4; i++) {
        int h = tid + i * 256;
        float o0 = 0, o1 = 0;
#pragma unroll
        for (int k = 0; k < 4; k++) {
            o0 = fmaf(p0[k], v[0][k][i], o0);
            o1 = fmaf(p1[k], v[1][k][i], o1);
        }
        short hh, ll;
        split2(o0, hh, ll); omzh[(size_t)b * 1024 + h] = hh; omzl[(size_t)b * 1024 + h] = ll;
        split2(o1, hh, ll); z2hh[(size_t)b * 1024 + h] = hh; z2hl[(size_t)b * 1024 + h] = ll;
    }
}

// ---------------------------------------------------------------------------
// generic mix. OP 0: p*q+b ; 1: tanh(p+q+b) ; 2: p+q+b.  OUT 1: bf16 hi/lo, 0: fp32
// ---------------------------------------------------------------------------
template <int OP, int OUT>
__global__ __launch_bounds__(256) void mix_kernel(
    const float* __restrict__ P, const float* __restrict__ Q,
    const float* __restrict__ bias, const float* __restrict__ wsc,
    float* __restrict__ of, short* __restrict__ oh, short* __restrict__ ol,
    float* __restrict__ G, int gcol)
{
    const int b = blockIdx.x, tid = threadIdx.x;
    const size_t base = (size_t)b * 4096;
    float v[4][4];
    float sc[4] = {0.f, 0.f, 0.f, 0.f};
#pragma unroll
    for (int k = 0; k < 4; k++)
#pragma unroll
        for (int i = 0; i < 4; i++) {
            int h = tid + i * 256;
            float pp = P[base + k * 1024 + h];
            float qq = Q[base + k * 1024 + h];
            float bk = bias[k * 1024 + h];
            float val;
            if (OP == 0)      val = fmaf(pp, qq, bk);
            else if (OP == 1) val = tanhf(pp + qq + bk);
            else              val = pp + qq + bk;
            v[k][i] = val;
            sc[k] = fmaf(val, wsc[h], sc[k]);
        }
    __shared__ float red[4][4];
    const int wid = tid >> 6, lane = tid & 63;
#pragma unroll
    for (int k = 0; k < 4; k++) {
        float s = wave_red(sc[k]);
        if (lane == 0) red[k][wid] = s;
    }
    __syncthreads();
    __shared__ float probs[4];
    if (tid == 0) {
        float s[4];
#pragma unroll
        for (int k = 0; k < 4; k++)
            s[k] = red[k][0] + red[k][1] + red[k][2] + red[k][3];
        int am = 0; float mx = s[0];
#pragma unroll
        for (int k = 1; k < 4; k++) if (s[k] > mx) { mx = s[k]; am = k; }
        float e[4], tot = 0.f;
#pragma unroll
        for (int k = 0; k < 4; k++) { e[k] = expf(s[k] - mx); tot += e[k]; }
#pragma unroll
        for (int k = 0; k < 4; k++) probs[k] = e[k] / tot;
        G[(size_t)b * 9 + gcol] = (float)am;
    }
    __syncthreads();
    float p0 = probs[0], p1 = probs[1], p2 = probs[2], p3 = probs[3];
#pragma unroll
    for (int i = 0; i < 4; i++) {
        int h = tid + i * 256;
        float o = p0 * v[0][i];
        o = fmaf(p1, v[1][i], o);
        o = fmaf(p2, v[2][i], o);
        o = fmaf(p3, v[3][i], o);
        if (OUT) {
            short hh, ll; split2(o, hh, ll);
            oh[(size_t)b * 1024 + h] = hh;
            ol[(size_t)b * 1024 + h] = ll;
        } else {
            of[(size_t)b * 1024 + h] = o;
        }
    }
}

// ---------------------------------------------------------------------------
extern "C" void kernel_launch(void* const* d_in, const int* in_sizes, int n_in,
                              void* d_out, int out_size, void* d_ws, size_t ws_size,
                              hipStream_t stream)
{
    const float* xs   = (const float*)d_in[0];
    const float* hs   = (const float*)d_in[1];
    const float* L    = (const float*)d_in[2];
    const float* R    = (const float*)d_in[3];
    const float* bias = (const float*)d_in[4];
    const float* w    = (const float*)d_in[5];

    float* out = (float*)d_out;
    float* G   = out + (size_t)B * H;

    // ws layout (160MB total, <=168MB known-safe):
    //  fp32: fA/fB/fD 32MB each (3 buffers via reuse schedule; fD hosts hsR01 16MB early)
    //  bf16 slots P1-P4 8MB each (hi 4MB + lo 4MB)
    //  weights Lth/Ltl/Rth/Rtl 8MB each
    char* wsb = (char*)d_ws;
    const size_t MB = 1024ull * 1024;
    float* fA = (float*)(wsb);
    float* fB = (float*)(wsb + 32 * MB);
    float* fD = (float*)(wsb + 64 * MB);
    short* P1h = (short*)(wsb + 96 * MB);  short* P1l = P1h + 2 * MB;
    short* P2h = (short*)(wsb + 104 * MB); short* P2l = P2h + 2 * MB;
    short* P3h = (short*)(wsb + 112 * MB); short* P3l = P3h + 2 * MB;
    short* P4h = (short*)(wsb + 120 * MB); short* P4l = P4h + 2 * MB;
    short* Lth = (short*)(wsb + 128 * MB);
    short* Ltl = (short*)(wsb + 136 * MB);
    short* Rth = (short*)(wsb + 144 * MB);
    short* Rtl = (short*)(wsb + 152 * MB);

    dim3 blk(256);
    dim3 g4(8, 16, 4), g2(8, 16, 2);

    conv_kernel<<<(B * H) / 256, blk, 0, stream>>>(xs, hs, P1h, P1l, P2h, P2l); // x->P1, h->P2
    wsplit_kernel<<<dim3(32, 32, 8), blk, 0, stream>>>(L, R, Lth, Ltl, Rth, Rtl);
    zero_g_kernel<<<(B * 9 + 255) / 256, blk, 0, stream>>>(G);

    // S0
    gemm_kernel<<<g4, blk, 0, stream>>>(P1h, P1l, Lth, Ltl, fA, 4096);  // xsL -> fA
    gemm_kernel<<<g4, blk, 0, stream>>>(P2h, P2l, Lth, Ltl, fB, 4096);  // hsL -> fB
    gemm_kernel<<<g2, blk, 0, stream>>>(P2h, P2l, Rth, Rtl, fD, 2048);  // hsR01 -> fD
    // E0: z1 -> P3, r -> P4
    e0_kernel<<<(B * H) / 256, blk, 0, stream>>>(fA, fD, bias, P3h, P3l, P4h, P4l);
    // S1a: z1R -> fD
    gemm_kernel<<<g4, blk, 0, stream>>>(P3h, P3l, Rth, Rtl, fD, 4096);
    // E1a: omz -> P2 (G5), z2h -> P3 (G7)
    mix2_kernel<<<B, blk, 0, stream>>>(fB, fD, bias, w, P2h, P2l, P3h, P3l, G);
    // S1b: rR -> fD
    gemm_kernel<<<g4, blk, 0, stream>>>(P4h, P4l, Rth, Rtl, fD, 4096);
    // E1b: rh = mix(hsL*rR+b) -> P1 (G3)
    mix_kernel<0, 1><<<B, blk, 0, stream>>>(fB, fD, bias, w, nullptr, P1h, P1l, G, 3);
    // S2: rhR -> fB, omzR -> fD
    gemm_kernel<<<g4, blk, 0, stream>>>(P1h, P1l, Rth, Rtl, fB, 4096);
    gemm_kernel<<<g4, blk, 0, stream>>>(P2h, P2l, Rth, Rtl, fD, 4096);
    // E2: h_tilde = mix(tanh(xsL+rhR+b)) -> P4 (G4)
    mix_kernel<1, 1><<<B, blk, 0, stream>>>(fA, fB, bias, w, nullptr, P4h, P4l, G, 4);
    // S3: htL -> fA, z2hR -> fB
    gemm_kernel<<<g4, blk, 0, stream>>>(P4h, P4l, Lth, Ltl, fA, 4096);
    gemm_kernel<<<g4, blk, 0, stream>>>(P3h, P3l, Rth, Rtl, fB, 4096);
    // E3: zh_tilde = mix(htL*omzR+b) -> P1 (G6)
    mix_kernel<0, 1><<<B, blk, 0, stream>>>(fA, fD, bias, w, nullptr, P1h, P1l, G, 6);
    // S4: zhL -> fD
    gemm_kernel<<<g4, blk, 0, stream>>>(P1h, P1l, Lth, Ltl, fD, 4096);
    // E4: h_next = mix(zhL+z2hR+b) -> out (G8)
    mix_kernel<2, 0><<<B, blk, 0, stream>>>(fD, fB, bias, w, out, nullptr, nullptr, G, 8);
}

// Round 3
// 605.095 us; speedup vs baseline: 3.5251x; 1.1330x over previous
//
#include <hip/hip_runtime.h>
#include <math.h>

#define B 2048
#define H 1024
#define HH (1024 * 1024)

typedef __attribute__((ext_vector_type(8))) short bf16x8;
typedef __attribute__((ext_vector_type(4))) float floatx4;

// ---------------- bf16 split helpers (RNE) ----------------
__device__ __forceinline__ short bf16_rne(float x) {
    unsigned int b = __float_as_uint(x);
    unsigned int r = (b + 0x7fffu + ((b >> 16) & 1u)) >> 16;
    return (short)r;
}
__device__ __forceinline__ float bf16_f(short h) {
    return __uint_as_float(((unsigned int)(unsigned short)h) << 16);
}
__device__ __forceinline__ void split2(float x, short& h, short& l) {
    h = bf16_rne(x);
    l = bf16_rne(x - bf16_f(h));
}
// candidate-3 vector load: fp32 if f!=null else hi+lo reconstruction
__device__ __forceinline__ float ld3(const float* f, const short* h, const short* l, size_t i) {
    if (f) return f[i];
    return bf16_f(h[i]) + bf16_f(l[i]);
}

// async global->LDS, 16B per lane; LDS dest = wave-uniform base + lane*16
__device__ __forceinline__ void gl16(const void* g, void* l) {
    __builtin_amdgcn_global_load_lds(
        (const __attribute__((address_space(1))) void*)g,
        (__attribute__((address_space(3))) void*)l, 16, 0, 0);
}

// ---------------------------------------------------------------------------
// Packed split-bf16 GEMM. Each blockIdx.z selects an independent job:
// C[m, n] += sum_k A[m,k]*W[k,n] for one 1024x1024 weight plane. A=Ah+Al,
// W=Wh+Wl (bf16 split, W pre-transposed to [n][k]). 4-term product.
// 128x128 tile, BK=32, 256 thr (2x2 waves, each 4x4 of 16x16x32 MFMA).
// LDS chunk-XOR swizzle -> fragment ds_read_b128 at free 2-way conflicts.
// ---------------------------------------------------------------------------
struct Job {
    const short* ah; const short* al;   // A hi/lo, [2048][1024]
    const short* wh; const short* wl;   // W^T hi/lo plane, [1024][1024]
    float* c;                           // output plane base (col-offset baked in)
    long ldc;                           // C row stride (floats)
};
struct Jobs { Job j[8]; };

__global__ __launch_bounds__(256, 2) void gemm_kernel(Jobs jobs)
{
    __shared__ short lds[4][4096];  // Ah,Al,Wh,Wl tiles: [128 rows][32 k]
    const Job jb = jobs.j[blockIdx.z];
    const int tid = threadIdx.x;
    const int w = tid >> 6, lane = tid & 63;
    const int wm = w >> 1, wn = w & 1;
    const int m0 = blockIdx.y * 128, n0 = blockIdx.x * 128;

    // staging: chunk cid = j*256+tid; row=cid>>2; src k-chunk = (cid&3)^((cid>>3)&3)
    const int cid0 = tid, cid1 = 256 + tid;
    const int r0 = cid0 >> 2, g0 = (((cid0 & 3) ^ ((cid0 >> 3) & 3)) << 3);
    const int r1 = cid1 >> 2, g1 = (((cid1 & 3) ^ ((cid1 >> 3) & 3)) << 3);

    const short* pah0 = jb.ah + (size_t)(m0 + r0) * H + g0;
    const short* pah1 = jb.ah + (size_t)(m0 + r1) * H + g1;
    const short* pal0 = jb.al + (size_t)(m0 + r0) * H + g0;
    const short* pal1 = jb.al + (size_t)(m0 + r1) * H + g1;
    const short* pbh0 = jb.wh + (size_t)(n0 + r0) * H + g0;
    const short* pbh1 = jb.wh + (size_t)(n0 + r1) * H + g1;
    const short* pbl0 = jb.wl + (size_t)(n0 + r0) * H + g0;
    const short* pbl1 = jb.wl + (size_t)(n0 + r1) * H + g1;

    short* sA0 = &lds[0][w * 512];        short* sA1 = &lds[0][2048 + w * 512];
    short* sa0 = &lds[1][w * 512];        short* sa1 = &lds[1][2048 + w * 512];
    short* sB0 = &lds[2][w * 512];        short* sB1 = &lds[2][2048 + w * 512];
    short* sb0 = &lds[3][w * 512];        short* sb1 = &lds[3][2048 + w * 512];

    const int fr = lane & 15, kc = lane >> 4;
    int aoff[4], boff[4];
#pragma unroll
    for (int t = 0; t < 4; t++) {
        int ar = wm * 64 + t * 16 + fr;
        aoff[t] = ar * 32 + ((kc ^ ((ar >> 1) & 3)) << 3);
        int br = wn * 64 + t * 16 + fr;
        boff[t] = br * 32 + ((kc ^ ((br >> 1) & 3)) << 3);
    }

    floatx4 acc[4][4];
#pragma unroll
    for (int i = 0; i < 4; i++)
#pragma unroll
        for (int j = 0; j < 4; j++) acc[i][j] = (floatx4)0.f;

    for (int ks = 0; ks < 32; ks++) {
        __syncthreads();
        gl16(pah0, sA0); gl16(pah1, sA1);
        gl16(pal0, sa0); gl16(pal1, sa1);
        gl16(pbh0, sB0); gl16(pbh1, sB1);
        gl16(pbl0, sb0); gl16(pbl1, sb1);
        pah0 += 32; pah1 += 32; pal0 += 32; pal1 += 32;
        pbh0 += 32; pbh1 += 32; pbl0 += 32; pbl1 += 32;
        __syncthreads();

        bf16x8 fah[4], fal[4], fbh[4], fbl[4];
#pragma unroll
        for (int t = 0; t < 4; t++) {
            fah[t] = *(const bf16x8*)&lds[0][aoff[t]];
            fal[t] = *(const bf16x8*)&lds[1][aoff[t]];
            fbh[t] = *(const bf16x8*)&lds[2][boff[t]];
            fbl[t] = *(const bf16x8*)&lds[3][boff[t]];
        }
#pragma unroll
        for (int mt = 0; mt < 4; mt++)
#pragma unroll
            for (int nt = 0; nt < 4; nt++) {
                acc[mt][nt] = __builtin_amdgcn_mfma_f32_16x16x32_bf16(fah[mt], fbh[nt], acc[mt][nt], 0, 0, 0);
                acc[mt][nt] = __builtin_amdgcn_mfma_f32_16x16x32_bf16(fah[mt], fbl[nt], acc[mt][nt], 0, 0, 0);
                acc[mt][nt] = __builtin_amdgcn_mfma_f32_16x16x32_bf16(fal[mt], fbh[nt], acc[mt][nt], 0, 0, 0);
                acc[mt][nt] = __builtin_amdgcn_mfma_f32_16x16x32_bf16(fal[mt], fbl[nt], acc[mt][nt], 0, 0, 0);
            }
    }

    // C/D layout: col = lane&15, row = (lane>>4)*4 + reg
    const int cr = (lane >> 4) * 4, cc = lane & 15;
#pragma unroll
    for (int mt = 0; mt < 4; mt++)
#pragma unroll
        for (int nt = 0; nt < 4; nt++) {
            float* Cp = jb.c + (size_t)(m0 + wm * 64 + mt * 16 + cr) * jb.ldc
                             + n0 + wn * 64 + nt * 16 + cc;
#pragma unroll
            for (int i = 0; i < 4; i++) Cp[(size_t)i * jb.ldc] = acc[mt][nt][i];
        }
}

// ---------------------------------------------------------------------------
// weights: planes 0..2 only (plane 3 is identity -- handled analytically).
// W[z][k][n] fp32 -> Wt_hi/lo[z][n][k] bf16 (transpose + split). zz<3: L, else R.
// ---------------------------------------------------------------------------
__global__ __launch_bounds__(256) void wsplit_kernel(
    const float* __restrict__ L, const float* __restrict__ R,
    short* __restrict__ Lth, short* __restrict__ Ltl,
    short* __restrict__ Rth, short* __restrict__ Rtl)
{
    const int zz = blockIdx.z;  // 0-2: L, 3-5: R
    const float* W = (zz < 3) ? L : R;
    short* Oh = (zz < 3) ? Lth : Rth;
    short* Ol = (zz < 3) ? Ltl : Rtl;
    const int z = (zz < 3) ? zz : zz - 3;
    const int k0 = blockIdx.y * 32, n0 = blockIdx.x * 32;
    __shared__ float t[32][33];
    const int tx = threadIdx.x & 31, ty = threadIdx.x >> 5;
    const float* src = W + (size_t)z * HH;
#pragma unroll
    for (int j = 0; j < 4; j++) {
        int r = ty + j * 8;
        t[r][tx] = src[(size_t)(k0 + r) * 1024 + n0 + tx];
    }
    __syncthreads();
    short* oh = Oh + (size_t)z * HH;
    short* ol = Ol + (size_t)z * HH;
#pragma unroll
    for (int j = 0; j < 4; j++) {
        int n = ty + j * 8;
        float v = t[tx][n];
        short hh, ll; split2(v, hh, ll);
        oh[(size_t)(n0 + n) * 1024 + k0 + tx] = hh;
        ol[(size_t)(n0 + n) * 1024 + k0 + tx] = ll;
    }
}

// inputs xs, hs -> bf16 hi/lo
__global__ __launch_bounds__(256) void conv_kernel(
    const float* __restrict__ xs, const float* __restrict__ hs,
    short* __restrict__ xh, short* __restrict__ xl,
    short* __restrict__ hh, short* __restrict__ hl)
{
    size_t i = (size_t)blockIdx.x * 256 + threadIdx.x;
    short a, b2; split2(xs[i], a, b2); xh[i] = a; xl[i] = b2;
    split2(hs[i], a, b2); hh[i] = a; hl[i] = b2;
}

__global__ __launch_bounds__(256) void zero_g_kernel(float* __restrict__ G)
{
    int idx = blockIdx.x * 256 + threadIdx.x;
    if (idx < B * 9) G[idx] = 0.f;
}

// z1 = sigmoid(xsL0+hsR0+b0), r = sigmoid(xsL1+hsR1+b1) -> bf16 hi/lo
__global__ __launch_bounds__(256) void e0_kernel(
    const float* __restrict__ xsL, const float* __restrict__ hsR,
    const float* __restrict__ bias,
    short* __restrict__ z1h, short* __restrict__ z1l,
    short* __restrict__ rh_, short* __restrict__ rl_)
{
    size_t idx = (size_t)blockIdx.x * 256 + threadIdx.x;
    int b = (int)(idx >> 10), h = (int)(idx & 1023);
    float z1 = 1.f / (1.f + expf(-(xsL[(size_t)b * 3072 + h] + hsR[(size_t)b * 2048 + h] + bias[h])));
    float r  = 1.f / (1.f + expf(-(xsL[(size_t)b * 3072 + 1024 + h] + hsR[(size_t)b * 2048 + 1024 + h] + bias[1024 + h])));
    short hh, ll;
    split2(z1, hh, ll); z1h[idx] = hh; z1l[idx] = ll;
    split2(r, hh, ll);  rh_[idx] = hh; rl_[idx] = ll;
}

__device__ __forceinline__ float wave_red(float v)
{
#pragma unroll
    for (int o = 32; o; o >>= 1) v += __shfl_down(v, o, 64);
    return v;
}

// ---------------------------------------------------------------------------
// mix2: omz = mix(1-(z1R+b)) -> G5 ; z2h = mix(hsL*z1R+b) -> G7.
// Planes 0..2 from GEMM buffers (stride 3072); candidate 3 analytic:
// omz3 = 1-(z1+b3), z2h3 = hs*z1+b3.  In/out P3 overlap is same-index safe.
// ---------------------------------------------------------------------------
__global__ __launch_bounds__(256) void mix2_kernel(
    const float* __restrict__ hsL, const float* __restrict__ z1R,
    const short* __restrict__ z1h_, const short* __restrict__ z1l_,
    const float* __restrict__ hsf,
    const float* __restrict__ bias, const float* __restrict__ wsc,
    short* __restrict__ omzh, short* __restrict__ omzl,
    short* __restrict__ z2hh, short* __restrict__ z2hl,
    float* __restrict__ G)
{
    const int b = blockIdx.x, tid = threadIdx.x;
    const size_t base = (size_t)b * 3072;
    const size_t vbase = (size_t)b * 1024;
    float v[2][4][4], sc[2][4];
#pragma unroll
    for (int m = 0; m < 2; m++)
#pragma unroll
        for (int k = 0; k < 4; k++) sc[m][k] = 0.f;
#pragma unroll
    for (int k = 0; k < 4; k++)
#pragma unroll
        for (int i = 0; i < 4; i++) {
            int h = tid + i * 256;
            float hl, zr;
            if (k < 3) {
                hl = hsL[base + k * 1024 + h];
                zr = z1R[base + k * 1024 + h];
            } else {
                hl = hsf[vbase + h];
                zr = bf16_f(z1h_[vbase + h]) + bf16_f(z1l_[vbase + h]);
            }
            float bk = bias[k * 1024 + h];
            float wv = wsc[h];
            float c = 1.0f - (zr + bk);
            float d = fmaf(hl, zr, bk);
            v[0][k][i] = c; v[1][k][i] = d;
            sc[0][k] = fmaf(c, wv, sc[0][k]);
            sc[1][k] = fmaf(d, wv, sc[1][k]);
        }
    __shared__ float red[8][4];
    const int wid = tid >> 6, lane = tid & 63;
#pragma unroll
    for (int m = 0; m < 2; m++)
#pragma unroll
        for (int k = 0; k < 4; k++) {
            float s = wave_red(sc[m][k]);
            if (lane == 0) red[m * 4 + k][wid] = s;
        }
    __syncthreads();
    __shared__ float probs[2][4];
    if (tid < 2) {
        int m = tid;
        float s[4];
#pragma unroll
        for (int k = 0; k < 4; k++)
            s[k] = red[m * 4 + k][0] + red[m * 4 + k][1] + red[m * 4 + k][2] + red[m * 4 + k][3];
        int am = 0; float mx = s[0];
#pragma unroll
        for (int k = 1; k < 4; k++) if (s[k] > mx) { mx = s[k]; am = k; }
        float e[4], tot = 0.f;
#pragma unroll
        for (int k = 0; k < 4; k++) { e[k] = expf(s[k] - mx); tot += e[k]; }
#pragma unroll
        for (int k = 0; k < 4; k++) probs[m][k] = e[k] / tot;
        G[(size_t)b * 9 + (m == 0 ? 5 : 7)] = (float)am;
    }
    __syncthreads();
    float p0[4], p1[4];
#pragma unroll
    for (int k = 0; k < 4; k++) { p0[k] = probs[0][k]; p1[k] = probs[1][k]; }
#pragma unroll
    for (int i = 0; i < 4; i++) {
        int h = tid + i * 256;
        float o0 = 0, o1 = 0;
#pragma unroll
        for (int k = 0; k < 4; k++) {
            o0 = fmaf(p0[k], v[0][k][i], o0);
            o1 = fmaf(p1[k], v[1][k][i], o1);
        }
        short hh, ll;
        split2(o0, hh, ll); omzh[vbase + h] = hh; omzl[vbase + h] = ll;
        split2(o1, hh, ll); z2hh[vbase + h] = hh; z2hl[vbase + h] = ll;
    }
}

// ---------------------------------------------------------------------------
// generic mix over 3 GEMM planes + analytic candidate 3.
// OP 0: p*q+b ; 1: tanh(p+q+b) ; 2: p+q+b.
// candidate-3 operands: fp32 ptr (exact input) or bf16 hi/lo pair (recon).
// out: bf16 pair (oh/ol) or fp32 (of).
// ---------------------------------------------------------------------------
template <int OP>
__global__ __launch_bounds__(256) void mix_kernel(
    const float* __restrict__ P, const float* __restrict__ Q,
    const float* __restrict__ a3f, const short* __restrict__ a3h, const short* __restrict__ a3l,
    const float* __restrict__ b3f, const short* __restrict__ b3h, const short* __restrict__ b3l,
    const float* __restrict__ bias, const float* __restrict__ wsc,
    float* __restrict__ of, short* __restrict__ oh, short* __restrict__ ol,
    float* __restrict__ G, int gcol)
{
    const int b = blockIdx.x, tid = threadIdx.x;
    const size_t base = (size_t)b * 3072;
    const size_t vbase = (size_t)b * 1024;
    float v[4][4];
    float sc[4] = {0.f, 0.f, 0.f, 0.f};
#pragma unroll
    for (int k = 0; k < 4; k++)
#pragma unroll
        for (int i = 0; i < 4; i++) {
            int h = tid + i * 256;
            float pp, qq;
            if (k < 3) {
                pp = P[base + k * 1024 + h];
                qq = Q[base + k * 1024 + h];
            } else {
                pp = ld3(a3f, a3h, a3l, vbase + h);
                qq = ld3(b3f, b3h, b3l, vbase + h);
            }
            float bk = bias[k * 1024 + h];
            float val;
            if (OP == 0)      val = fmaf(pp, qq, bk);
            else if (OP == 1) val = tanhf(pp + qq + bk);
            else              val = pp + qq + bk;
            v[k][i] = val;
            sc[k] = fmaf(val, wsc[h], sc[k]);
        }
    __shared__ float red[4][4];
    const int wid = tid >> 6, lane = tid & 63;
#pragma unroll
    for (int k = 0; k < 4; k++) {
        float s = wave_red(sc[k]);
        if (lane == 0) red[k][wid] = s;
    }
    __syncthreads();
    __shared__ float probs[4];
    if (tid == 0) {
        float s[4];
#pragma unroll
        for (int k = 0; k < 4; k++)
            s[k] = red[k][0] + red[k][1] + red[k][2] + red[k][3];
        int am = 0; float mx = s[0];
#pragma unroll
        for (int k = 1; k < 4; k++) if (s[k] > mx) { mx = s[k]; am = k; }
        float e[4], tot = 0.f;
#pragma unroll
        for (int k = 0; k < 4; k++) { e[k] = expf(s[k] - mx); tot += e[k]; }
#pragma unroll
        for (int k = 0; k < 4; k++) probs[k] = e[k] / tot;
        G[(size_t)b * 9 + gcol] = (float)am;
    }
    __syncthreads();
    float p0 = probs[0], p1 = probs[1], p2 = probs[2], p3 = probs[3];
#pragma unroll
    for (int i = 0; i < 4; i++) {
        int h = tid + i * 256;
        float o = p0 * v[0][i];
        o = fmaf(p1, v[1][i], o);
        o = fmaf(p2, v[2][i], o);
        o = fmaf(p3, v[3][i], o);
        if (oh) {
            short hh, ll; split2(o, hh, ll);
            oh[vbase + h] = hh;
            ol[vbase + h] = ll;
        } else {
            of[vbase + h] = o;
        }
    }
}

// ---------------------------------------------------------------------------
extern "C" void kernel_launch(void* const* d_in, const int* in_sizes, int n_in,
                              void* d_out, int out_size, void* d_ws, size_t ws_size,
                              hipStream_t stream)
{
    const float* xs   = (const float*)d_in[0];
    const float* hs   = (const float*)d_in[1];
    const float* L    = (const float*)d_in[2];
    const float* R    = (const float*)d_in[3];
    const float* bias = (const float*)d_in[4];
    const float* w    = (const float*)d_in[5];

    float* out = (float*)d_out;
    float* G   = out + (size_t)B * H;

    // ws layout (152 MB):
    //   fA/fB/fC/fD: 3-plane fp32 C-buffers, B x 3072, 24 MB each
    //   P1..P4: bf16 hi/lo vector pairs, 8 MB each
    //   weights: L^T/R^T hi/lo planes 0..2, 6 MB each
    char* wsb = (char*)d_ws;
    const size_t MB = 1024ull * 1024;
    float* fA = (float*)(wsb);
    float* fB = (float*)(wsb + 24 * MB);
    float* fC = (float*)(wsb + 48 * MB);
    float* fD = (float*)(wsb + 72 * MB);
    short* P1h = (short*)(wsb + 96 * MB);  short* P1l = P1h + 2 * MB;  // x -> rh -> zh
    short* P2h = (short*)(wsb + 104 * MB); short* P2l = P2h + 2 * MB;  // h -> omz
    short* P3h = (short*)(wsb + 112 * MB); short* P3l = P3h + 2 * MB;  // z1 -> z2h
    short* P4h = (short*)(wsb + 120 * MB); short* P4l = P4h + 2 * MB;  // r -> h_tilde
    short* Lth = (short*)(wsb + 128 * MB);
    short* Ltl = (short*)(wsb + 134 * MB);
    short* Rth = (short*)(wsb + 140 * MB);
    short* Rtl = (short*)(wsb + 146 * MB);

    dim3 blk(256);
    const float* NF = nullptr; const short* NS = nullptr;

    conv_kernel<<<(B * H) / 256, blk, 0, stream>>>(xs, hs, P1h, P1l, P2h, P2l);
    wsplit_kernel<<<dim3(32, 32, 6), blk, 0, stream>>>(L, R, Lth, Ltl, Rth, Rtl);
    zero_g_kernel<<<(B * 9 + 255) / 256, blk, 0, stream>>>(G);

    // S0: xsL(3)->fA, hsL(3)->fB, hsR01(2)->fC  [8 planes, 1024 blocks]
    Jobs s0{};
    for (int p = 0; p < 3; p++) {
        s0.j[p]     = { P1h, P1l, Lth + (size_t)p * HH, Ltl + (size_t)p * HH, fA + p * 1024, 3072 };
        s0.j[3 + p] = { P2h, P2l, Lth + (size_t)p * HH, Ltl + (size_t)p * HH, fB + p * 1024, 3072 };
    }
    for (int p = 0; p < 2; p++)
        s0.j[6 + p] = { P2h, P2l, Rth + (size_t)p * HH, Rtl + (size_t)p * HH, fC + p * 1024, 2048 };
    gemm_kernel<<<dim3(8, 16, 8), blk, 0, stream>>>(s0);

    // E0: z1 -> P3, r -> P4
    e0_kernel<<<(B * H) / 256, blk, 0, stream>>>(fA, fC, bias, P3h, P3l, P4h, P4l);

    // S1: z1R(3)->fD, rR(3)->fC  [768 blocks]
    Jobs s1{};
    for (int p = 0; p < 3; p++) {
        s1.j[p]     = { P3h, P3l, Rth + (size_t)p * HH, Rtl + (size_t)p * HH, fD + p * 1024, 3072 };
        s1.j[3 + p] = { P4h, P4l, Rth + (size_t)p * HH, Rtl + (size_t)p * HH, fC + p * 1024, 3072 };
    }
    gemm_kernel<<<dim3(8, 16, 6), blk, 0, stream>>>(s1);

    // E1a: omz -> P2 (G5), z2h -> P3 (G7); cand3: 1-z1, hs*z1
    mix2_kernel<<<B, blk, 0, stream>>>(fB, fD, P3h, P3l, hs, bias, w,
                                       P2h, P2l, P3h, P3l, G);
    // E1b: rh = mix(hsL*rR+b) -> P1 (G3); cand3 = hs*r
    mix_kernel<0><<<B, blk, 0, stream>>>(fB, fC, hs, NS, NS, NF, P4h, P4l,
                                         bias, w, nullptr, P1h, P1l, G, 3);

    // S2: rhR(3)->fB, omzR(3)->fC  [768 blocks]
    Jobs s2{};
    for (int p = 0; p < 3; p++) {
        s2.j[p]     = { P1h, P1l, Rth + (size_t)p * HH, Rtl + (size_t)p * HH, fB + p * 1024, 3072 };
        s2.j[3 + p] = { P2h, P2l, Rth + (size_t)p * HH, Rtl + (size_t)p * HH, fC + p * 1024, 3072 };
    }
    gemm_kernel<<<dim3(8, 16, 6), blk, 0, stream>>>(s2);

    // E2: h_tilde = mix(tanh(xsL+rhR+b)) -> P4 (G4); cand3 = tanh(x+rh)
    mix_kernel<1><<<B, blk, 0, stream>>>(fA, fB, xs, NS, NS, NF, P1h, P1l,
                                         bias, w, nullptr, P4h, P4l, G, 4);

    // S3: htL(3)->fA, z2hR(3)->fB  [768 blocks]
    Jobs s3{};
    for (int p = 0; p < 3; p++) {
        s3.j[p]     = { P4h, P4l, Lth + (size_t)p * HH, Ltl + (size_t)p * HH, fA + p * 1024, 3072 };
        s3.j[3 + p] = { P3h, P3l, Rth + (size_t)p * HH, Rtl + (size_t)p * HH, fB + p * 1024, 3072 };
    }
    gemm_kernel<<<dim3(8, 16, 6), blk, 0, stream>>>(s3);

    // E3: zh_tilde = mix(htL*omzR+b) -> P1 (G6); cand3 = ht*omz
    mix_kernel<0><<<B, blk, 0, stream>>>(fA, fC, NF, P4h, P4l, NF, P2h, P2l,
                                         bias, w, nullptr, P1h, P1l, G, 6);

    // S4: zhL(3)->fC  [384 blocks]
    Jobs s4{};
    for (int p = 0; p < 3; p++)
        s4.j[p] = { P1h, P1l, Lth + (size_t)p * HH, Ltl + (size_t)p * HH, fC + p * 1024, 3072 };
    gemm_kernel<<<dim3(8, 16, 3), blk, 0, stream>>>(s4);

    // E4: h_next = mix(zhL+z2hR+b) -> out (G8); cand3 = zh+z2h
    mix_kernel<2><<<B, blk, 0, stream>>>(fC, fB, NF, P1h, P1l, NF, P3h, P3l,
                                         bias, w, out, nullptr, nullptr, G, 8);
}